// Round 3
// baseline (411.136 us; speedup 1.0000x reference)
//
#include <hip/hip_runtime.h>
#include <math.h>

#define T 256
#define RS 36          // padded row stride (floats): conflict-free, 16B-aligned rows
#define H 8            // band height
#define NB 4           // bands per image

// LDS float offsets
#define OFF_A   0      // XB (3 x 12 x RS = 1296) / H3B (8 x 12 x RS = 3456)
#define OFF_B   3456   // T1 (16 x 10 x RS = 5760) / T4 (16 x 10 x RS = 5760)
#define OFF_ROT 9216   // 96
#define OFF_ANG 9312   // 4
#define OFF_Q   9316   // 4
#define OFF_RED 9320   // 16
#define LDS_FLOATS 9344

__global__ __launch_bounds__(T) void fused_kernel(
    const float* __restrict__ x,
    const float* __restrict__ c1w, const float* __restrict__ c1b,
    const float* __restrict__ c2w, const float* __restrict__ c2b,
    const float* __restrict__ fcw, const float* __restrict__ fcb,
    const float* __restrict__ qw,
    const float* __restrict__ f2w, const float* __restrict__ f2b,
    const float* __restrict__ d1w, const float* __restrict__ d1b,
    const float* __restrict__ d2w, const float* __restrict__ d2b,
    float* __restrict__ out) {
    __shared__ float lds[LDS_FLOATS];
    float* A   = lds + OFF_A;
    float* Bf  = lds + OFF_B;
    float* ROT = lds + OFF_ROT;

    const int tid = threadIdx.x;
    const int b   = blockIdx.x;

    // zero all LDS (borders of all tiles must be 0 for SAME padding)
    for (int i = tid; i < LDS_FLOATS; i += T) lds[i] = 0.f;
    __syncthreads();

    // per-block Rot-matrix precompute (tiny, batch-independent)
    if (tid < 12) {
        float phi = qw[tid * 3 + 0], theta = qw[tid * 3 + 1], omega = qw[tid * 3 + 2];
        float a = 0.5f * (phi + omega), d = 0.5f * (phi - omega);
        float st, ct; sincosf(0.5f * theta, &st, &ct);
        float sa, ca; sincosf(a, &sa, &ca);
        float sd, cd; sincosf(d, &sd, &cd);
        float* o = ROT + tid * 8;
        o[0] = ct * ca;  o[1] = -ct * sa;
        o[2] = -st * cd; o[3] = -st * sd;
        o[4] = st * cd;  o[5] = -st * sd;
        o[6] = ct * ca;  o[7] = ct * sa;
    }

    float part[4] = {0.f, 0.f, 0.f, 0.f};

    // ================= encoder: banded conv1 -> conv2 -> fc partials =======
    for (int band = 0; band < NB; ++band) {
        const int y0 = band * H;

        // ---- load x window rows y0-2 .. y0+9 (3 ch x 12 rows), OOB -> 0 ----
        for (int i = tid; i < 3 * 12 * 32; i += T) {
            int c = i / 384, rem = i - c * 384, r = rem >> 5, cx = rem & 31;
            int gy = y0 - 2 + r;
            float v = 0.f;
            if (gy >= 0 && gy < 32) v = x[b * 3072 + c * 1024 + gy * 32 + cx];
            A[(c * 12 + r) * RS + 1 + cx] = v;
        }
        __syncthreads();

        // ---- conv1 3->16 on rows gy = y0-1 .. y0+8 (10 rows) -> T1 ----
        for (int p = tid; p < 320; p += T) {
            int r1 = p >> 5, cx = p & 31;
            int gy = y0 - 1 + r1;
            const float* ib = A + r1 * RS + cx;
            float acc[16];
#pragma unroll
            for (int oc = 0; oc < 16; ++oc) acc[oc] = c1b[oc];
#pragma unroll
            for (int ic = 0; ic < 3; ++ic) {
                float v[9];
#pragma unroll
                for (int ky = 0; ky < 3; ++ky)
#pragma unroll
                    for (int kx = 0; kx < 3; ++kx)
                        v[ky * 3 + kx] = ib[ic * 432 + ky * RS + kx];
#pragma unroll
                for (int oc = 0; oc < 16; ++oc) {
                    const float* wp = c1w + (oc * 3 + ic) * 9;
#pragma unroll
                    for (int k = 0; k < 9; ++k)
                        acc[oc] = fmaf(wp[k], v[k], acc[oc]);
                }
            }
            const bool oob = (gy < 0) || (gy > 31);
            float* ob = Bf + r1 * RS + 1 + cx;
#pragma unroll
            for (int oc = 0; oc < 16; ++oc)
                ob[oc * 360] = oob ? 0.f : fmaxf(acc[oc], 0.f);
        }
        __syncthreads();

        // ---- conv2 16->8 on band rows + fc partial accumulate ----
        {
            const int ry = tid >> 5, cx = tid & 31;
            const float* ib = Bf + ry * RS + cx;
            float acc[8];
#pragma unroll
            for (int oc = 0; oc < 8; ++oc) acc[oc] = c2b[oc];
#pragma unroll 2
            for (int ic = 0; ic < 16; ++ic) {
                float v[9];
#pragma unroll
                for (int ky = 0; ky < 3; ++ky)
#pragma unroll
                    for (int kx = 0; kx < 3; ++kx)
                        v[ky * 3 + kx] = ib[ic * 360 + ky * RS + kx];
#pragma unroll
                for (int oc = 0; oc < 8; ++oc) {
                    const float* wp = c2w + (oc * 16 + ic) * 9;
#pragma unroll
                    for (int k = 0; k < 9; ++k)
                        acc[oc] = fmaf(wp[k], v[k], acc[oc]);
                }
            }
            const int gj = y0 * 32 + tid;   // global h2 pixel index (y0+ry)*32+cx
#pragma unroll
            for (int oc = 0; oc < 8; ++oc) {
                float h = fmaxf(acc[oc], 0.f);
#pragma unroll
                for (int o = 0; o < 4; ++o)
                    part[o] = fmaf(h, fcw[o * 8192 + oc * 1024 + gj], part[o]);
            }
        }
        __syncthreads();
    }

    // ================= fc reduce -> angles ==================================
#pragma unroll
    for (int off = 32; off; off >>= 1)
#pragma unroll
        for (int o = 0; o < 4; ++o)
            part[o] += __shfl_down(part[o], off);
    {
        int wid = tid >> 6;
        if ((tid & 63) == 0) {
#pragma unroll
            for (int o = 0; o < 4; ++o) lds[OFF_RED + wid * 4 + o] = part[o];
        }
    }
    __syncthreads();
    if (tid == 0) {
#pragma unroll
        for (int o = 0; o < 4; ++o) {
            float s = fcb[o];
            for (int w = 0; w < 4; ++w) s += lds[OFF_RED + w * 4 + o];
            lds[OFF_ANG + o] = s;
        }
    }
    __syncthreads();

    // ================= 4-qubit statevector sim (wave 0) =====================
    if (tid < 64) {
        const int s = tid & 15;
        float re = (s == 0) ? 1.f : 0.f, im = 0.f;
#pragma unroll
        for (int w = 0; w < 4; ++w) {
            float a = lds[OFF_ANG + w] * 0.5f;
            float sn, c; sincosf(a, &sn, &c);
            int stride = 1 << (3 - w);
            float pr = __shfl_xor(re, stride);
            float pi = __shfl_xor(im, stride);
            float nre = c * re + sn * pi;
            float nim = c * im - sn * pr;
            re = nre; im = nim;
        }
#pragma unroll
        for (int l = 0; l < 3; ++l) {
#pragma unroll
            for (int w = 0; w < 4; ++w) {
                const float* U = ROT + (l * 4 + w) * 8;
                int stride = 1 << (3 - w);
                bool bit = (s & stride) != 0;
                float pr = __shfl_xor(re, stride);
                float pi = __shfl_xor(im, stride);
                float cAr = bit ? U[6] : U[0], cAi = bit ? U[7] : U[1];
                float cBr = bit ? U[4] : U[2], cBi = bit ? U[5] : U[3];
                float nre = cAr * re - cAi * im + cBr * pr - cBi * pi;
                float nim = cAr * im + cAi * re + cBr * pi + cBi * pr;
                re = nre; im = nim;
            }
            const int r = (l % 3) + 1;
#pragma unroll
            for (int w = 0; w < 4; ++w) {
                int cs = 1 << (3 - w);
                int ts = 1 << (3 - ((w + r) & 3));
                float pr = __shfl_xor(re, ts);
                float pi = __shfl_xor(im, ts);
                if (s & cs) { re = pr; im = pi; }
            }
        }
        float pprob = re * re + im * im;
        float ev[4];
#pragma unroll
        for (int w = 0; w < 4; ++w)
            ev[w] = (s & (1 << (3 - w))) ? -pprob : pprob;
#pragma unroll
        for (int m = 1; m <= 8; m <<= 1)
#pragma unroll
            for (int w = 0; w < 4; ++w)
                ev[w] += __shfl_xor(ev[w], m);
        if (tid == 0) {
#pragma unroll
            for (int w = 0; w < 4; ++w) lds[OFF_Q + w] = ev[w];
        }
    }
    __syncthreads();

    const float q0 = lds[OFF_Q + 0], q1 = lds[OFF_Q + 1];
    const float q2 = lds[OFF_Q + 2], q3 = lds[OFF_Q + 3];

    // ================= decoder: banded fc2 -> dconv1 -> dconv2 ==============
    for (int band = 0; band < NB; ++band) {
        const int y0 = band * H;

        // ---- fc2: h3 window rows y0-2 .. y0+9 (8 ch x 12 rows), OOB -> 0 ---
        for (int i = tid; i < 8 * 12 * 32; i += T) {
            int c = i / 384, rem = i - c * 384, r = rem >> 5, cx = rem & 31;
            int gy = y0 - 2 + r;
            float v = 0.f;
            if (gy >= 0 && gy < 32) {
                int idx = c * 1024 + gy * 32 + cx;
                const float4 wv = *reinterpret_cast<const float4*>(f2w + idx * 4);
                v = f2b[idx];
                v = fmaf(q0, wv.x, v);
                v = fmaf(q1, wv.y, v);
                v = fmaf(q2, wv.z, v);
                v = fmaf(q3, wv.w, v);
            }
            A[(c * 12 + r) * RS + 1 + cx] = v;
        }
        __syncthreads();

        // ---- dconv1 8->16 on rows gy = y0-1 .. y0+8 (10 rows) -> T4 ----
        for (int p = tid; p < 320; p += T) {
            int r1 = p >> 5, cx = p & 31;
            int gy = y0 - 1 + r1;
            const float* ib = A + r1 * RS + cx;
            float acc[16];
#pragma unroll
            for (int oc = 0; oc < 16; ++oc) acc[oc] = d1b[oc];
#pragma unroll 2
            for (int ic = 0; ic < 8; ++ic) {
                float v[9];
#pragma unroll
                for (int ky = 0; ky < 3; ++ky)
#pragma unroll
                    for (int kx = 0; kx < 3; ++kx)
                        v[ky * 3 + kx] = ib[ic * 432 + ky * RS + kx];
#pragma unroll
                for (int oc = 0; oc < 16; ++oc) {
                    const float* wp = d1w + (oc * 8 + ic) * 9;
#pragma unroll
                    for (int k = 0; k < 9; ++k)
                        acc[oc] = fmaf(wp[k], v[k], acc[oc]);
                }
            }
            const bool oob = (gy < 0) || (gy > 31);
            float* ob = Bf + r1 * RS + 1 + cx;
#pragma unroll
            for (int oc = 0; oc < 16; ++oc)
                ob[oc * 360] = oob ? 0.f : fmaxf(acc[oc], 0.f);
        }
        __syncthreads();

        // ---- dconv2 16->3 + sigmoid -> global out (band rows) ----
        {
            const int ry = tid >> 5, cx = tid & 31;
            const float* ib = Bf + ry * RS + cx;
            float acc[3];
#pragma unroll
            for (int oc = 0; oc < 3; ++oc) acc[oc] = d2b[oc];
#pragma unroll 2
            for (int ic = 0; ic < 16; ++ic) {
                float v[9];
#pragma unroll
                for (int ky = 0; ky < 3; ++ky)
#pragma unroll
                    for (int kx = 0; kx < 3; ++kx)
                        v[ky * 3 + kx] = ib[ic * 360 + ky * RS + kx];
#pragma unroll
                for (int oc = 0; oc < 3; ++oc) {
                    const float* wp = d2w + (oc * 16 + ic) * 9;
#pragma unroll
                    for (int k = 0; k < 9; ++k)
                        acc[oc] = fmaf(wp[k], v[k], acc[oc]);
                }
            }
            float* ob = out + b * 3072 + (y0 + ry) * 32 + cx;
#pragma unroll
            for (int oc = 0; oc < 3; ++oc)
                ob[oc * 1024] = 1.f / (1.f + expf(-acc[oc]));
        }
        __syncthreads();
    }
}

// ---------------- launch ----------------------------------------------------
extern "C" void kernel_launch(void* const* d_in, const int* in_sizes, int n_in,
                              void* d_out, int out_size, void* d_ws, size_t ws_size,
                              hipStream_t stream) {
    const float* x   = (const float*)d_in[0];
    const float* c1w = (const float*)d_in[1];
    const float* c1b = (const float*)d_in[2];
    const float* c2w = (const float*)d_in[3];
    const float* c2b = (const float*)d_in[4];
    const float* fcw = (const float*)d_in[5];
    const float* fcb = (const float*)d_in[6];
    const float* qw  = (const float*)d_in[7];
    const float* f2w = (const float*)d_in[8];
    const float* f2b = (const float*)d_in[9];
    const float* d1w = (const float*)d_in[10];
    const float* d1b = (const float*)d_in[11];
    const float* d2w = (const float*)d_in[12];
    const float* d2b = (const float*)d_in[13];
    float* out = (float*)d_out;

    fused_kernel<<<2048, T, 0, stream>>>(
        x, c1w, c1b, c2w, c2b, fcw, fcb, qw, f2w, f2b,
        d1w, d1b, d2w, d2b, out);
}